// Round 7
// baseline (289.596 us; speedup 1.0000x reference)
//
#include <hip/hip_runtime.h>

#define NN 100000
#define NE 600000
#define SPILL_CAP 8192
#define NB 196            // buckets of 512 nodes: 196*512 = 100352 >= NN
#define BSH 9             // bucket = dst >> 9
#define BCAP 4096         // mean 3061/bucket, sigma 55 -> +18.8 sigma headroom
#define NBB 293           // pass-1 blocks: 293*2048 >= NE

typedef __attribute__((ext_vector_type(8))) short short8;   // 8 bf16 (4 VGPRs)
typedef __attribute__((ext_vector_type(4))) float f32x4;    // MFMA C/D frag

static __device__ __forceinline__ float bf2f_lo(unsigned int u) {
  union { unsigned int i; float f; } v;
  v.i = u << 16;
  return v.f;
}
static __device__ __forceinline__ float bf2f_hi(unsigned int u) {
  union { unsigned int i; float f; } v;
  v.i = u & 0xffff0000u;
  return v.f;
}
static __device__ __forceinline__ unsigned short f2bf(float f) {
  union { float f; unsigned int i; } v;
  v.f = f;
  unsigned int x = v.i;
  x += 0x7FFFu + ((x >> 16) & 1u);  // round-to-nearest-even
  return (unsigned short)(x >> 16);
}

static __device__ __forceinline__ void async_cp16(const unsigned short* g, unsigned short* l) {
  __builtin_amdgcn_global_load_lds(
      (const __attribute__((address_space(1))) unsigned int*)g,
      (__attribute__((address_space(3))) unsigned int*)l,
      16, 0, 0);
}

// ---------- fused prologue (r6 structure, proven) ----------
// blocks [0,293): edge bucketing (2048 edges/block)
// blocks [293,3418): cast x fp32->bf16, 4 float4/thread
// blocks [3418,3994): 6 weight transposes
__global__ __launch_bounds__(256) void k_prep(
    const float* __restrict__ x, unsigned short* __restrict__ xb,
    const float* __restrict__ W1l, const float* __restrict__ W1r,
    const float* __restrict__ W2l, const float* __restrict__ W2r,
    const float* __restrict__ W3l, const float* __restrict__ W3r,
    unsigned short* __restrict__ t1l, unsigned short* __restrict__ t1r,
    unsigned short* __restrict__ t2l, unsigned short* __restrict__ t2r,
    unsigned short* __restrict__ t3l, unsigned short* __restrict__ t3r,
    const int* __restrict__ src, const int* __restrict__ dst,
    int2* __restrict__ bucketBuf, int* __restrict__ bCnt) {
  __shared__ int hist[NB];
  __shared__ int basep[NB];
  __shared__ int lpos[NB];
  const int bid = blockIdx.x;
  const int tid = threadIdx.x;
  if (bid < NBB) {                        // pass-1 edge bucketing
    if (tid < NB) { hist[tid] = 0; lpos[tid] = 0; }
    __syncthreads();
    const int e0 = bid * 2048 + tid;
    int dv[8], sv[8];
    #pragma unroll
    for (int j = 0; j < 8; j++) {
      int e = e0 + j * 256;
      if (e < NE) { dv[j] = dst[e]; sv[j] = src[e]; } else dv[j] = -1;
    }
    #pragma unroll
    for (int j = 0; j < 8; j++)
      if (dv[j] >= 0) atomicAdd(&hist[dv[j] >> BSH], 1);
    __syncthreads();
    if (tid < NB) {
      int h = hist[tid];
      basep[tid] = h ? atomicAdd(&bCnt[tid * 16], h) : 0;   // 64B-padded lines
    }
    __syncthreads();
    #pragma unroll
    for (int j = 0; j < 8; j++)
      if (dv[j] >= 0) {
        int b = dv[j] >> BSH;
        int p = atomicAdd(&lpos[b], 1) + basep[b];          // LDS atomic
        if (p < BCAP) bucketBuf[(size_t)b * BCAP + p] = make_int2(dv[j], sv[j]);
      }
  } else if (bid < 3418) {                // cast: 3,200,000 float4s, 1024/block
    int base = (bid - NBB) * 1024 + tid;
    const float4* xf = (const float4*)x;
    float4 f0 = xf[base];
    float4 f1 = xf[base + 256];
    float4 f2 = xf[base + 512];
    float4 f3 = xf[base + 768];
    ushort4* ob = (ushort4*)xb;
    ushort4 o0, o1, o2, o3;
    o0.x = f2bf(f0.x); o0.y = f2bf(f0.y); o0.z = f2bf(f0.z); o0.w = f2bf(f0.w);
    o1.x = f2bf(f1.x); o1.y = f2bf(f1.y); o1.z = f2bf(f1.z); o1.w = f2bf(f1.w);
    o2.x = f2bf(f2.x); o2.y = f2bf(f2.y); o2.z = f2bf(f2.z); o2.w = f2bf(f2.w);
    o3.x = f2bf(f3.x); o3.y = f2bf(f3.y); o3.z = f2bf(f3.z); o3.w = f2bf(f3.w);
    ob[base] = o0; ob[base + 256] = o1; ob[base + 512] = o2; ob[base + 768] = o3;
  } else {                                // 147456 transpose elems
    int i = (bid - 3418) * 256 + tid;
    const float* W; unsigned short* T; int ks, N;
    if (i < 65536)        { if (i < 32768) { W = W1l; T = t1l; } else { W = W1r; T = t1r; i -= 32768; } ks = 7; N = 256; }
    else if (i < 131072)  { if (i < 98304) { W = W2l; T = t2l; i -= 65536; } else { W = W2r; T = t2r; i -= 98304; } ks = 8; N = 128; }
    else                  { if (i < 139264) { W = W3l; T = t3l; i -= 131072; } else { W = W3r; T = t3r; i -= 139264; } ks = 7; N = 64; }
    int K = 1 << ks;
    int n = i >> ks, k = i & (K - 1);
    T[i] = f2bf(W[(size_t)k * N + n]);
  }
}

// ---------- pass-2 CSR build: one block per bucket, LDS atomics only ----------
__global__ __launch_bounds__(1024) void k_csr2(
    const int2* __restrict__ bucketBuf, const int* __restrict__ bCnt,
    int* __restrict__ cnt, int* __restrict__ S,
    int* __restrict__ spillc, int* __restrict__ spill) {
  __shared__ int lcnt[512];
  const int b = blockIdx.x;
  const int tid = threadIdx.x;
  const int lo = b << BSH;
  if (tid < 512) lcnt[tid] = 0;
  __syncthreads();
  int n = bCnt[b * 16];
  if (n > BCAP) n = BCAP;
  for (int i = tid; i < n; i += 1024) {
    int2 pr = bucketBuf[(size_t)b * BCAP + i];
    int p = atomicAdd(&lcnt[pr.x - lo], 1);
    if (p < 32) S[pr.x * 32 + p] = pr.y;
    else {
      int q = atomicAdd(spillc, 1);
      if (q < SPILL_CAP) { spill[2 * q] = pr.x; spill[2 * q + 1] = pr.y; }
    }
  }
  __syncthreads();
  if (tid < 512) {
    int v = lo + tid;
    if (v < NN) cnt[v] = lcnt[tid];
  }
}

// ---------- gather-mean, C=128 rows: 4 nodes/wave, 16 lanes/node ----------
template <bool ADD>
__global__ __launch_bounds__(256) void k_gather4_128(const unsigned short* __restrict__ feat,
                                                     const unsigned short* __restrict__ t,
                                                     const int* __restrict__ cnt,
                                                     const int* __restrict__ S,
                                                     const int* __restrict__ spillc,
                                                     const int* __restrict__ spill,
                                                     unsigned short* __restrict__ outp) {
  const int tid = threadIdx.x;
  const int sl = tid & 15;
  const int v = blockIdx.x * 16 + (tid >> 4);
  const int deg = cnt[v];
  const int cap = deg < 16 ? deg : 16;
  const int dcap = deg < 32 ? deg : 32;
  int idx = (sl < cap) ? S[v * 32 + sl] : 0;
  const uint4* fp = (const uint4*)feat;             // 16 uint4 per row

  float a0 = 0.f, a1 = 0.f, a2 = 0.f, a3 = 0.f, a4 = 0.f, a5 = 0.f, a6 = 0.f, a7 = 0.f;
  auto accum = [&](uint4 u) {
    a0 += bf2f_lo(u.x); a1 += bf2f_hi(u.x);
    a2 += bf2f_lo(u.y); a3 += bf2f_hi(u.y);
    a4 += bf2f_lo(u.z); a5 += bf2f_hi(u.z);
    a6 += bf2f_lo(u.w); a7 += bf2f_hi(u.w);
  };
  {
    uint4 u[8];
    #pragma unroll
    for (int e = 0; e < 8; e++) {
      int ie = __shfl(idx, e, 16);
      u[e] = fp[(size_t)ie * 16 + sl];
    }
    #pragma unroll
    for (int e = 0; e < 8; e++) {
      if (e >= deg) { u[e].x = 0; u[e].y = 0; u[e].z = 0; u[e].w = 0; }
      accum(u[e]);
    }
  }
  if (deg > 8) {
    uint4 u[8];
    #pragma unroll
    for (int e = 0; e < 8; e++) {
      int ie = __shfl(idx, 8 + e, 16);
      u[e] = fp[(size_t)ie * 16 + sl];
    }
    #pragma unroll
    for (int e = 0; e < 8; e++) {
      if (8 + e >= deg) { u[e].x = 0; u[e].y = 0; u[e].z = 0; u[e].w = 0; }
      accum(u[e]);
    }
  }
  for (int e = 16; e < dcap; e++) accum(fp[(size_t)S[v * 32 + e] * 16 + sl]);  // deg in (16,32]
  if (deg > 32) {                                    // never in practice
    int L = *spillc; if (L > SPILL_CAP) L = SPILL_CAP;
    for (int i2 = 0; i2 < L; i2++)
      if (spill[2 * i2] == v) accum(fp[(size_t)spill[2 * i2 + 1] * 16 + sl]);
  }

  float inv = 1.0f / (float)(deg > 1 ? deg : 1);
  float r0, r1, r2, r3, r4, r5, r6, r7;
  if (ADD) {
    uint4 tu = ((const uint4*)t)[(size_t)v * 16 + sl];
    r0 = fmaxf(a0 * inv + bf2f_lo(tu.x), 0.f); r1 = fmaxf(a1 * inv + bf2f_hi(tu.x), 0.f);
    r2 = fmaxf(a2 * inv + bf2f_lo(tu.y), 0.f); r3 = fmaxf(a3 * inv + bf2f_hi(tu.y), 0.f);
    r4 = fmaxf(a4 * inv + bf2f_lo(tu.z), 0.f); r5 = fmaxf(a5 * inv + bf2f_hi(tu.z), 0.f);
    r6 = fmaxf(a6 * inv + bf2f_lo(tu.w), 0.f); r7 = fmaxf(a7 * inv + bf2f_hi(tu.w), 0.f);
  } else {
    r0 = a0 * inv; r1 = a1 * inv; r2 = a2 * inv; r3 = a3 * inv;
    r4 = a4 * inv; r5 = a5 * inv; r6 = a6 * inv; r7 = a7 * inv;
  }
  uint4 o;
  o.x = (unsigned int)f2bf(r0) | ((unsigned int)f2bf(r1) << 16);
  o.y = (unsigned int)f2bf(r2) | ((unsigned int)f2bf(r3) << 16);
  o.z = (unsigned int)f2bf(r4) | ((unsigned int)f2bf(r5) << 16);
  o.w = (unsigned int)f2bf(r6) | ((unsigned int)f2bf(r7) << 16);
  ((uint4*)outp)[(size_t)v * 16 + sl] = o;
}

// ---------- L3 fused: out = log_softmax(mean(g[src]) + t), C=64 rows ----------
__global__ __launch_bounds__(256) void k_gather8_lsm(const unsigned short* __restrict__ g,
                                                     const unsigned short* __restrict__ t,
                                                     const int* __restrict__ cnt,
                                                     const int* __restrict__ S,
                                                     const int* __restrict__ spillc,
                                                     const int* __restrict__ spill,
                                                     float* __restrict__ out) {
  const int tid = threadIdx.x;
  const int sl = tid & 7;
  const int v = blockIdx.x * 32 + (tid >> 3);
  const int deg = cnt[v];
  const int cap8 = deg < 8 ? deg : 8;
  const int cap16 = deg < 16 ? deg : 16;
  const int dcap = deg < 32 ? deg : 32;
  int idxA = (sl < cap8) ? S[v * 32 + sl] : 0;
  int idxB = (8 + sl < cap16) ? S[v * 32 + 8 + sl] : 0;
  const uint4* fp = (const uint4*)g;                // 8 uint4 per row

  float a0 = 0.f, a1 = 0.f, a2 = 0.f, a3 = 0.f, a4 = 0.f, a5 = 0.f, a6 = 0.f, a7 = 0.f;
  auto accum = [&](uint4 u) {
    a0 += bf2f_lo(u.x); a1 += bf2f_hi(u.x);
    a2 += bf2f_lo(u.y); a3 += bf2f_hi(u.y);
    a4 += bf2f_lo(u.z); a5 += bf2f_hi(u.z);
    a6 += bf2f_lo(u.w); a7 += bf2f_hi(u.w);
  };
  {
    uint4 u[8];
    #pragma unroll
    for (int e = 0; e < 8; e++) {
      int ie = __shfl(idxA, e, 8);
      u[e] = fp[(size_t)ie * 8 + sl];
    }
    #pragma unroll
    for (int e = 0; e < 8; e++) {
      if (e >= deg) { u[e].x = 0; u[e].y = 0; u[e].z = 0; u[e].w = 0; }
      accum(u[e]);
    }
  }
  if (deg > 8) {
    uint4 u[8];
    #pragma unroll
    for (int e = 0; e < 8; e++) {
      int ie = __shfl(idxB, e, 8);
      u[e] = fp[(size_t)ie * 8 + sl];
    }
    #pragma unroll
    for (int e = 0; e < 8; e++) {
      if (8 + e >= deg) { u[e].x = 0; u[e].y = 0; u[e].z = 0; u[e].w = 0; }
      accum(u[e]);
    }
  }
  for (int e = 16; e < dcap; e++) accum(fp[(size_t)S[v * 32 + e] * 8 + sl]);
  if (deg > 32) {                                    // never in practice
    int L = *spillc; if (L > SPILL_CAP) L = SPILL_CAP;
    for (int i2 = 0; i2 < L; i2++)
      if (spill[2 * i2] == v) accum(fp[(size_t)spill[2 * i2 + 1] * 8 + sl]);
  }

  float inv = 1.0f / (float)(deg > 1 ? deg : 1);
  uint4 tu = ((const uint4*)t)[(size_t)v * 8 + sl];
  float v0 = a0 * inv + bf2f_lo(tu.x), v1 = a1 * inv + bf2f_hi(tu.x);
  float v2 = a2 * inv + bf2f_lo(tu.y), v3 = a3 * inv + bf2f_hi(tu.y);
  float v4 = a4 * inv + bf2f_lo(tu.z), v5 = a5 * inv + bf2f_hi(tu.z);
  float v6 = a6 * inv + bf2f_lo(tu.w), v7 = a7 * inv + bf2f_hi(tu.w);
  float m = fmaxf(fmaxf(fmaxf(v0, v1), fmaxf(v2, v3)), fmaxf(fmaxf(v4, v5), fmaxf(v6, v7)));
  #pragma unroll
  for (int s = 4; s; s >>= 1) m = fmaxf(m, __shfl_xor(m, s, 8));
  float sum = __expf(v0 - m) + __expf(v1 - m) + __expf(v2 - m) + __expf(v3 - m)
            + __expf(v4 - m) + __expf(v5 - m) + __expf(v6 - m) + __expf(v7 - m);
  #pragma unroll
  for (int s = 4; s; s >>= 1) sum += __shfl_xor(sum, s, 8);
  float ls = m + __logf(sum);
  float4* op = (float4*)out;
  op[(size_t)v * 16 + sl * 2 + 0] = make_float4(v0 - ls, v1 - ls, v2 - ls, v3 - ls);
  op[(size_t)v * 16 + sl * 2 + 1] = make_float4(v4 - ls, v5 - ls, v6 - ls, v7 - ls);
}

// ---------- bf16 MFMA GEMM, BK=64, XOR-swizzled LDS, coalesced repack epilogue ----------
template <int BN, bool DUAL>
__global__ __launch_bounds__(BN * 2) void k_gmm(
    const unsigned short* __restrict__ A1, const unsigned short* __restrict__ Wt1,
    const unsigned short* __restrict__ A2, const unsigned short* __restrict__ Wt2,
    const float* __restrict__ bias, int M, int K, int N,
    unsigned short* __restrict__ out1, unsigned short* __restrict__ out2, int relu) {
  constexpr int NWAVE = BN / 32;          // 4 or 2
  constexpr int ACHUNKS = 16;             // 128 rows / 8 rows-per-chunk
  constexpr int BCHUNKS = BN / 8;
  constexpr int STR = BN + 8;             // repack slab row stride
  __shared__ unsigned short smem[128 * 64 + BN * 64];
  unsigned short* As = smem;
  unsigned short* Bs = smem + 128 * 64;
  const int t = threadIdx.x;
  const int w = t >> 6, lane = t & 63;
  const int quad = lane >> 4, l15 = lane & 15;
  const int wm = w & 1, wn = w >> 1;      // BN=64: wn==0
  const int m0 = blockIdx.x * 128;
  const int n0 = DUAL ? blockIdx.y * BN : 0;
  const int srow = lane >> 3;             // row in 8-row chunk
  const int sk = (((lane & 7) ^ (srow & 7)) * 8);  // swizzled source k-offset (elems)

  const unsigned short* Wt = DUAL ? Wt1 : (blockIdx.y ? Wt2 : Wt1);
  unsigned short* out = DUAL ? out1 : (blockIdx.y ? out2 : out1);
  const float* bs = DUAL ? bias : (blockIdx.y ? bias : nullptr);

  f32x4 acc[4][4];
  #pragma unroll
  for (int i = 0; i < 4; i++)
    #pragma unroll
    for (int j = 0; j < 4; j++) acc[i][j] = (f32x4){0.f, 0.f, 0.f, 0.f};

  const int nph = DUAL ? 2 : 1;
  for (int ph = 0; ph < nph; ph++) {
    const unsigned short* A = (DUAL && ph) ? A2 : A1;
    const unsigned short* W = (DUAL && ph) ? Wt2 : Wt;
    for (int k0 = 0; k0 < K; k0 += 64) {
      #pragma unroll
      for (int c = w; c < ACHUNKS; c += NWAVE) {
        int rg = m0 + c * 8 + srow;
        if (rg >= M) rg = M - 1;          // clamp; epilogue guards stores
        async_cp16(A + (size_t)rg * K + k0 + sk, As + c * 512);
      }
      #pragma unroll
      for (int c = w; c < BCHUNKS; c += NWAVE) {
        async_cp16(W + (size_t)(n0 + c * 8 + srow) * K + k0 + sk, Bs + c * 512);
      }
      __syncthreads();
      short8 af[2][4], bfr[2][4];
      #pragma unroll
      for (int kh = 0; kh < 2; kh++) {
        #pragma unroll
        for (int mt = 0; mt < 4; mt++) {
          int r = wm * 64 + mt * 16 + l15;
          int cc = (kh * 4 + quad) ^ (r & 7);
          af[kh][mt] = *(const short8*)&As[r * 64 + cc * 8];
        }
        #pragma unroll
        for (int nt = 0; nt < 4; nt++) {
          int r = wn * 64 + nt * 16 + l15;
          int cc = (kh * 4 + quad) ^ (r & 7);
          bfr[kh][nt] = *(const short8*)&Bs[r * 64 + cc * 8];
        }
      }
      #pragma unroll
      for (int kh = 0; kh < 2; kh++)
        #pragma unroll
        for (int mt = 0; mt < 4; mt++)
          #pragma unroll
          for (int nt = 0; nt < 4; nt++)
            acc[mt][nt] = __builtin_amdgcn_mfma_f32_16x16x32_bf16(af[kh][mt], bfr[kh][nt], acc[mt][nt], 0, 0, 0);
      __syncthreads();
    }
  }

  // epilogue: repack per-mt slab (32 rows x BN cols bf16) in LDS -> 16B coalesced stores
  float bia[4];
  #pragma unroll
  for (int nt = 0; nt < 4; nt++)
    bia[nt] = bs ? bs[n0 + wn * 64 + nt * 16 + l15] : 0.f;
  constexpr int CH_PER_ROW = BN / 8;
  constexpr int TOT_CH = 32 * CH_PER_ROW;
  for (int mt = 0; mt < 4; mt++) {
    __syncthreads();
    #pragma unroll
    for (int nt = 0; nt < 4; nt++) {
      int col = wn * 64 + nt * 16 + l15;
      #pragma unroll
      for (int r = 0; r < 4; r++) {
        float v = acc[mt][nt][r] + bia[nt];
        if (relu) v = fmaxf(v, 0.f);
        smem[(wm * 16 + quad * 4 + r) * STR + col] = f2bf(v);
      }
    }
    __syncthreads();
    #pragma unroll
    for (int c = t; c < TOT_CH; c += BN * 2) {
      int row = c / CH_PER_ROW, ofs = (c % CH_PER_ROW) * 8;
      int m = m0 + (row >> 4) * 64 + mt * 16 + (row & 15);
      if (m < M)
        *(short8*)(out + (size_t)m * N + n0 + ofs) = *(const short8*)&smem[row * STR + ofs];
    }
  }
}

// ---------- FUSED L2-gather + L3-GEMM: h2 never touches HBM ----------
// Each block: (1) gathers its 128 rows h2 = relu(mean(g2[src]) + t2) directly
// into the XOR-swizzled LDS A-layout (lane sl holds exactly k-group sl -> one
// ds_write_b128 at pos (sl&7)^(r&7)); (2) GEMM vs stacked [t3l;t3r] (K=128,
// 128 out cols: 0..63 -> g3 (no bias), 64..127 -> t3 + b3). Saves h2 w+r
// (~51MB HBM) + one dispatch.
__global__ __launch_bounds__(256) void k_gath_gmm3(
    const unsigned short* __restrict__ g2, const unsigned short* __restrict__ t2,
    const int* __restrict__ cnt, const int* __restrict__ S,
    const int* __restrict__ spillc, const int* __restrict__ spill,
    const unsigned short* __restrict__ Wt, const float* __restrict__ bias,
    int M, unsigned short* __restrict__ g3, unsigned short* __restrict__ t3) {
  __shared__ unsigned short As2[2][128 * 64];   // swizzled h2 tile (2 k-chunks)
  __shared__ unsigned short Bs[128 * 64];       // W tile / repack slab
  const int tid = threadIdx.x;
  const int m0 = blockIdx.x * 128;
  const int sl = tid & 15;
  const uint4* fp = (const uint4*)g2;           // 16 uint4 per row

  // ---- gather phase: 8 passes x 16 nodes (4 nodes/wave, same as standalone) ----
  for (int p = 0; p < 8; p++) {
    const int r = p * 16 + (tid >> 4);
    const int v = m0 + r;
    const int vv = v < M ? v : M - 1;
    const int deg = cnt[vv];
    const int cap = deg < 16 ? deg : 16;
    const int dcap = deg < 32 ? deg : 32;
    int idx = (sl < cap) ? S[vv * 32 + sl] : 0;
    float a0 = 0.f, a1 = 0.f, a2 = 0.f, a3 = 0.f, a4 = 0.f, a5 = 0.f, a6 = 0.f, a7 = 0.f;
    auto accum = [&](uint4 u) {
      a0 += bf2f_lo(u.x); a1 += bf2f_hi(u.x);
      a2 += bf2f_lo(u.y); a3 += bf2f_hi(u.y);
      a4 += bf2f_lo(u.z); a5 += bf2f_hi(u.z);
      a6 += bf2f_lo(u.w); a7 += bf2f_hi(u.w);
    };
    {
      uint4 u[8];
      #pragma unroll
      for (int e = 0; e < 8; e++) {
        int ie = __shfl(idx, e, 16);
        u[e] = fp[(size_t)ie * 16 + sl];
      }
      #pragma unroll
      for (int e = 0; e < 8; e++) {
        if (e >= deg) { u[e].x = 0; u[e].y = 0; u[e].z = 0; u[e].w = 0; }
        accum(u[e]);
      }
    }
    if (deg > 8) {
      uint4 u[8];
      #pragma unroll
      for (int e = 0; e < 8; e++) {
        int ie = __shfl(idx, 8 + e, 16);
        u[e] = fp[(size_t)ie * 16 + sl];
      }
      #pragma unroll
      for (int e = 0; e < 8; e++) {
        if (8 + e >= deg) { u[e].x = 0; u[e].y = 0; u[e].z = 0; u[e].w = 0; }
        accum(u[e]);
      }
    }
    for (int e = 16; e < dcap; e++) accum(fp[(size_t)S[vv * 32 + e] * 16 + sl]);
    if (deg > 32) {
      int L = *spillc; if (L > SPILL_CAP) L = SPILL_CAP;
      for (int i2 = 0; i2 < L; i2++)
        if (spill[2 * i2] == vv) accum(fp[(size_t)spill[2 * i2 + 1] * 16 + sl]);
    }
    float inv = 1.0f / (float)(deg > 1 ? deg : 1);
    uint4 tu = ((const uint4*)t2)[(size_t)vv * 16 + sl];
    float r0 = fmaxf(a0 * inv + bf2f_lo(tu.x), 0.f), r1 = fmaxf(a1 * inv + bf2f_hi(tu.x), 0.f);
    float r2 = fmaxf(a2 * inv + bf2f_lo(tu.y), 0.f), r3 = fmaxf(a3 * inv + bf2f_hi(tu.y), 0.f);
    float r4 = fmaxf(a4 * inv + bf2f_lo(tu.z), 0.f), r5 = fmaxf(a5 * inv + bf2f_hi(tu.z), 0.f);
    float r6 = fmaxf(a6 * inv + bf2f_lo(tu.w), 0.f), r7 = fmaxf(a7 * inv + bf2f_hi(tu.w), 0.f);
    uint4 o;
    o.x = (unsigned int)f2bf(r0) | ((unsigned int)f2bf(r1) << 16);
    o.y = (unsigned int)f2bf(r2) | ((unsigned int)f2bf(r3) << 16);
    o.z = (unsigned int)f2bf(r4) | ((unsigned int)f2bf(r5) << 16);
    o.w = (unsigned int)f2bf(r6) | ((unsigned int)f2bf(r7) << 16);
    // swizzled LDS write: k-chunk = sl>>3, pos = (sl&7)^(r&7), 16B aligned
    *(uint4*)&As2[sl >> 3][r * 64 + (((sl & 7) ^ (r & 7)) * 8)] = o;
  }
  __syncthreads();

  // ---- GEMM phase: 4 waves 2m x 2n over 128 rows x 128 out cols, K=128 ----
  const int w = tid >> 6, lane = tid & 63;
  const int quad = lane >> 4, l15 = lane & 15;
  const int wm = w & 1, wn = w >> 1;
  const int srow = lane >> 3;
  const int sk = (((lane & 7) ^ (srow & 7)) * 8);
  f32x4 acc[4][4];
  #pragma unroll
  for (int i = 0; i < 4; i++)
    #pragma unroll
    for (int j = 0; j < 4; j++) acc[i][j] = (f32x4){0.f, 0.f, 0.f, 0.f};

  for (int kc = 0; kc < 2; kc++) {
    #pragma unroll
    for (int c = w; c < 16; c += 4)
      async_cp16(Wt + (size_t)(c * 8 + srow) * 128 + kc * 64 + sk, Bs + c * 512);
    __syncthreads();
    short8 af[2][4], bfr[2][4];
    #pragma unroll
    for (int kh = 0; kh < 2; kh++) {
      #pragma unroll
      for (int mt = 0; mt < 4; mt++) {
        int r = wm * 64 + mt * 16 + l15;
        int cc = (kh * 4 + quad) ^ (r & 7);
        af[kh][mt] = *(const short8*)&As2[kc][r * 64 + cc * 8];
      }
      #pragma unroll
      for (int nt = 0; nt < 4; nt++) {
        int r = wn * 64 + nt * 16 + l15;
        int cc = (kh * 4 + quad) ^ (r & 7);
        bfr[kh][nt] = *(const short8*)&Bs[r * 64 + cc * 8];
      }
    }
    #pragma unroll
    for (int kh = 0; kh < 2; kh++)
      #pragma unroll
      for (int mt = 0; mt < 4; mt++)
        #pragma unroll
        for (int nt = 0; nt < 4; nt++)
          acc[mt][nt] = __builtin_amdgcn_mfma_f32_16x16x32_bf16(af[kh][mt], bfr[kh][nt], acc[mt][nt], 0, 0, 0);
    __syncthreads();
  }

  // epilogue: repack slab (32 rows x 128 cols), split stores to g3 / t3
  constexpr int STR = 136;
  unsigned short* slab = Bs;
  float bia[4];
  #pragma unroll
  for (int nt = 0; nt < 4; nt++) {
    int col = wn * 64 + nt * 16 + l15;
    bia[nt] = (col >= 64) ? bias[col - 64] : 0.f;
  }
  for (int mt = 0; mt < 4; mt++) {
    __syncthreads();
    #pragma unroll
    for (int nt = 0; nt < 4; nt++) {
      int col = wn * 64 + nt * 16 + l15;
      #pragma unroll
      for (int r = 0; r < 4; r++)
        slab[(wm * 16 + quad * 4 + r) * STR + col] = f2bf(acc[mt][nt][r] + bia[nt]);
    }
    __syncthreads();
    #pragma unroll
    for (int c = tid; c < 512; c += 256) {
      int row = c >> 4, ofs = (c & 15) * 8;
      int m = m0 + (row >> 4) * 64 + mt * 16 + (row & 15);
      if (m < M) {
        if (ofs < 64)
          *(short8*)(g3 + (size_t)m * 64 + ofs) = *(const short8*)&slab[row * STR + ofs];
        else
          *(short8*)(t3 + (size_t)m * 64 + ofs - 64) = *(const short8*)&slab[row * STR + ofs];
      }
    }
  }
}

extern "C" void kernel_launch(void* const* d_in, const int* in_sizes, int n_in,
                              void* d_out, int out_size, void* d_ws, size_t ws_size,
                              hipStream_t stream) {
  const float* x   = (const float*)d_in[0];
  const int*   ei  = (const int*)d_in[1];
  const float* W1l = (const float*)d_in[2];
  const float* W1r = (const float*)d_in[3];
  const float* b1  = (const float*)d_in[4];
  const float* W2l = (const float*)d_in[5];
  const float* W2r = (const float*)d_in[6];
  const float* b2  = (const float*)d_in[7];
  const float* W3l = (const float*)d_in[8];
  const float* W3r = (const float*)d_in[9];
  const float* b3  = (const float*)d_in[10];
  float* out = (float*)d_out;
  const int* src = ei;
  const int* dst = ei + NE;

  char* w = (char*)d_ws;
  auto alloc = [&](size_t bytes) {
    char* p = w;
    w += (bytes + 255) & ~(size_t)255;
    return p;
  };
  int* cnt    = (int*)alloc(NN * sizeof(int));          // fully written by k_csr2
  int* combo  = (int*)alloc((256 + NB * 16) * sizeof(int));  // spillc + padded bCnt
  int* spillc = combo;
  int* bCnt   = combo + 256;
  int* S      = (int*)alloc((size_t)NN * 32 * sizeof(int));
  int* spill  = (int*)alloc(2 * SPILL_CAP * sizeof(int));
  int2* bucketBuf = (int2*)alloc((size_t)NB * BCAP * sizeof(int2));  // 6.4MB
  unsigned short* xb = (unsigned short*)alloc((size_t)NN * 128 * 2);
  unsigned short* mb = (unsigned short*)alloc((size_t)NN * 128 * 2);  // L1 mean; aliased as g2
  unsigned short* h1 = (unsigned short*)alloc((size_t)NN * 256 * 2);  // aliased as g3|t3 later
  unsigned short* t2 = (unsigned short*)alloc((size_t)NN * 128 * 2);
  unsigned short* t1l = (unsigned short*)alloc(128 * 256 * 2);
  unsigned short* t1r = (unsigned short*)alloc(128 * 256 * 2);
  unsigned short* t2l = (unsigned short*)alloc(256 * 128 * 2);
  unsigned short* t2r = (unsigned short*)alloc(256 * 128 * 2);
  unsigned short* tS3 = (unsigned short*)alloc((size_t)128 * 128 * 2); // stacked [t3l;t3r]
  unsigned short* t3l = tS3;
  unsigned short* t3r = tS3 + 64 * 128;
  unsigned short* g2 = mb;                       // reuse: mb dead after L1 GEMM
  unsigned short* g3 = h1;                       // reuse: h1 dead after L2 GEMM
  unsigned short* t3 = h1 + (size_t)NN * 64;

  hipMemsetAsync(combo, 0, (256 + NB * 16) * sizeof(int), stream);
  // fused pass-1 bucketing + cast + weight transpose
  k_prep<<<3994, 256, 0, stream>>>(x, xb, W1l, W1r, W2l, W2r, W3l, W3r,
                                   t1l, t1r, t2l, t2r, t3l, t3r,
                                   src, dst, bucketBuf, bCnt);
  // pass-2: per-bucket CSR build (LDS atomics, local S writes)
  k_csr2<<<NB, 1024, 0, stream>>>(bucketBuf, bCnt, cnt, S, spillc, spill);

  const int MB = (NN + 127) / 128;  // 782
  const int GB16 = NN / 16;         // 6250
  const int GB32 = NN / 32;         // 3125
  // L1: h1 = relu(mean(xb)@W1l + xb@W1r + b1)
  k_gather4_128<false><<<GB16, 256, 0, stream>>>(xb, nullptr, cnt, S, spillc, spill, mb);
  k_gmm<128, true><<<dim3(MB, 2), 256, 0, stream>>>(mb, t1l, xb, t1r, b1, NN, 128, 256, h1, nullptr, 1);
  // L2: g2 = h1@W2l ; t2 = h1@W2r + b2
  k_gmm<128, false><<<dim3(MB, 2), 256, 0, stream>>>(h1, t2l, nullptr, t2r, b2, NN, 256, 128, g2, t2, 0);
  // L3 fused: h2(LDS) = relu(mean(g2[src])+t2) ; g3 = h2@t3l ; t3 = h2@t3r + b3
  k_gath_gmm3<<<MB, 256, 0, stream>>>(g2, t2, cnt, S, spillc, spill, tS3, b3, NN, g3, t3);
  // out = log_softmax(mean(g3[src]) + t3)
  k_gather8_lsm<<<GB32, 256, 0, stream>>>(g3, t3, cnt, S, spillc, spill, out);
}

// Round 8
// 283.264 us; speedup vs baseline: 1.0224x; 1.0224x over previous
//
#include <hip/hip_runtime.h>

#define NN 100000
#define NE 600000
#define SPILL_CAP 8192
#define NB 196            // buckets of 512 nodes: 196*512 = 100352 >= NN
#define BSH 9             // bucket = dst >> 9
#define BCAP 4096         // mean 3061/bucket, sigma 55 -> +18.8 sigma headroom
#define NBB 293           // pass-1 blocks: 293*2048 >= NE

typedef __attribute__((ext_vector_type(8))) short short8;   // 8 bf16 (4 VGPRs)
typedef __attribute__((ext_vector_type(4))) float f32x4;    // MFMA C/D frag

static __device__ __forceinline__ float bf2f_lo(unsigned int u) {
  union { unsigned int i; float f; } v;
  v.i = u << 16;
  return v.f;
}
static __device__ __forceinline__ float bf2f_hi(unsigned int u) {
  union { unsigned int i; float f; } v;
  v.i = u & 0xffff0000u;
  return v.f;
}
static __device__ __forceinline__ unsigned short f2bf(float f) {
  union { float f; unsigned int i; } v;
  v.f = f;
  unsigned int x = v.i;
  x += 0x7FFFu + ((x >> 16) & 1u);  // round-to-nearest-even
  return (unsigned short)(x >> 16);
}

static __device__ __forceinline__ void async_cp16(const unsigned short* g, unsigned short* l) {
  __builtin_amdgcn_global_load_lds(
      (const __attribute__((address_space(1))) unsigned int*)g,
      (__attribute__((address_space(3))) unsigned int*)l,
      16, 0, 0);
}

// ---------- fused prologue (r6 structure, proven best) ----------
// blocks [0,293): edge bucketing (2048 edges/block); entries PACKED 32-bit:
//   (d&511)<<17 | s  (d-lo<512 -> 9 bits, s<100000 -> 17 bits)
// blocks [293,3418): cast x fp32->bf16, 4 float4/thread
// blocks [3418,3994): 6 weight transposes
__global__ __launch_bounds__(256) void k_prep(
    const float* __restrict__ x, unsigned short* __restrict__ xb,
    const float* __restrict__ W1l, const float* __restrict__ W1r,
    const float* __restrict__ W2l, const float* __restrict__ W2r,
    const float* __restrict__ W3l, const float* __restrict__ W3r,
    unsigned short* __restrict__ t1l, unsigned short* __restrict__ t1r,
    unsigned short* __restrict__ t2l, unsigned short* __restrict__ t2r,
    unsigned short* __restrict__ t3l, unsigned short* __restrict__ t3r,
    const int* __restrict__ src, const int* __restrict__ dst,
    unsigned int* __restrict__ bucketBuf, int* __restrict__ bCnt) {
  __shared__ int hist[NB];
  __shared__ int basep[NB];
  __shared__ int lpos[NB];
  const int bid = blockIdx.x;
  const int tid = threadIdx.x;
  if (bid < NBB) {                        // pass-1 edge bucketing
    if (tid < NB) { hist[tid] = 0; lpos[tid] = 0; }
    __syncthreads();
    const int e0 = bid * 2048 + tid;
    int dv[8], sv[8];
    #pragma unroll
    for (int j = 0; j < 8; j++) {
      int e = e0 + j * 256;
      if (e < NE) { dv[j] = dst[e]; sv[j] = src[e]; } else dv[j] = -1;
    }
    #pragma unroll
    for (int j = 0; j < 8; j++)
      if (dv[j] >= 0) atomicAdd(&hist[dv[j] >> BSH], 1);
    __syncthreads();
    if (tid < NB) {
      int h = hist[tid];
      basep[tid] = h ? atomicAdd(&bCnt[tid * 16], h) : 0;   // 64B-padded lines
    }
    __syncthreads();
    #pragma unroll
    for (int j = 0; j < 8; j++)
      if (dv[j] >= 0) {
        int b = dv[j] >> BSH;
        int p = atomicAdd(&lpos[b], 1) + basep[b];          // LDS atomic
        if (p < BCAP)
          bucketBuf[(size_t)b * BCAP + p] =
              ((unsigned int)(dv[j] & 511) << 17) | (unsigned int)sv[j];
      }
  } else if (bid < 3418) {                // cast: 3,200,000 float4s, 1024/block
    int base = (bid - NBB) * 1024 + tid;
    const float4* xf = (const float4*)x;
    float4 f0 = xf[base];
    float4 f1 = xf[base + 256];
    float4 f2 = xf[base + 512];
    float4 f3 = xf[base + 768];
    ushort4* ob = (ushort4*)xb;
    ushort4 o0, o1, o2, o3;
    o0.x = f2bf(f0.x); o0.y = f2bf(f0.y); o0.z = f2bf(f0.z); o0.w = f2bf(f0.w);
    o1.x = f2bf(f1.x); o1.y = f2bf(f1.y); o1.z = f2bf(f1.z); o1.w = f2bf(f1.w);
    o2.x = f2bf(f2.x); o2.y = f2bf(f2.y); o2.z = f2bf(f2.z); o2.w = f2bf(f2.w);
    o3.x = f2bf(f3.x); o3.y = f2bf(f3.y); o3.z = f2bf(f3.z); o3.w = f2bf(f3.w);
    ob[base] = o0; ob[base + 256] = o1; ob[base + 512] = o2; ob[base + 768] = o3;
  } else {                                // 147456 transpose elems
    int i = (bid - 3418) * 256 + tid;
    const float* W; unsigned short* T; int ks, N;
    if (i < 65536)        { if (i < 32768) { W = W1l; T = t1l; } else { W = W1r; T = t1r; i -= 32768; } ks = 7; N = 256; }
    else if (i < 131072)  { if (i < 98304) { W = W2l; T = t2l; i -= 65536; } else { W = W2r; T = t2r; i -= 98304; } ks = 8; N = 128; }
    else                  { if (i < 139264) { W = W3l; T = t3l; i -= 131072; } else { W = W3r; T = t3r; i -= 139264; } ks = 7; N = 64; }
    int K = 1 << ks;
    int n = i >> ks, k = i & (K - 1);
    T[i] = f2bf(W[(size_t)k * N + n]);
  }
}

// ---------- pass-2 CSR build: one block per bucket, LDS atomics only ----------
__global__ __launch_bounds__(1024) void k_csr2(
    const unsigned int* __restrict__ bucketBuf, const int* __restrict__ bCnt,
    int* __restrict__ cnt, int* __restrict__ S,
    int* __restrict__ spillc, int* __restrict__ spill) {
  __shared__ int lcnt[512];
  const int b = blockIdx.x;
  const int tid = threadIdx.x;
  const int lo = b << BSH;
  if (tid < 512) lcnt[tid] = 0;
  __syncthreads();
  int n = bCnt[b * 16];
  if (n > BCAP) n = BCAP;
  for (int i = tid; i < n; i += 1024) {
    unsigned int pr = bucketBuf[(size_t)b * BCAP + i];
    int dl = (int)(pr >> 17);
    int s = (int)(pr & 0x1FFFFu);
    int p = atomicAdd(&lcnt[dl], 1);
    if (p < 32) S[(lo + dl) * 32 + p] = s;
    else {
      int q = atomicAdd(spillc, 1);
      if (q < SPILL_CAP) { spill[2 * q] = lo + dl; spill[2 * q + 1] = s; }
    }
  }
  __syncthreads();
  if (tid < 512) {
    int v = lo + tid;
    if (v < NN) cnt[v] = lcnt[tid];
  }
}

// ---------- gather-mean, C=128 rows: 4 nodes/wave, 16 lanes/node ----------
template <bool ADD>
__global__ __launch_bounds__(256) void k_gather4_128(const unsigned short* __restrict__ feat,
                                                     const unsigned short* __restrict__ t,
                                                     const int* __restrict__ cnt,
                                                     const int* __restrict__ S,
                                                     const int* __restrict__ spillc,
                                                     const int* __restrict__ spill,
                                                     unsigned short* __restrict__ outp) {
  const int tid = threadIdx.x;
  const int sl = tid & 15;
  const int v = blockIdx.x * 16 + (tid >> 4);
  const int deg = cnt[v];
  const int cap = deg < 16 ? deg : 16;
  const int dcap = deg < 32 ? deg : 32;
  int idx = (sl < cap) ? S[v * 32 + sl] : 0;
  const uint4* fp = (const uint4*)feat;             // 16 uint4 per row

  float a0 = 0.f, a1 = 0.f, a2 = 0.f, a3 = 0.f, a4 = 0.f, a5 = 0.f, a6 = 0.f, a7 = 0.f;
  auto accum = [&](uint4 u) {
    a0 += bf2f_lo(u.x); a1 += bf2f_hi(u.x);
    a2 += bf2f_lo(u.y); a3 += bf2f_hi(u.y);
    a4 += bf2f_lo(u.z); a5 += bf2f_hi(u.z);
    a6 += bf2f_lo(u.w); a7 += bf2f_hi(u.w);
  };
  {
    uint4 u[8];
    #pragma unroll
    for (int e = 0; e < 8; e++) {
      int ie = __shfl(idx, e, 16);
      u[e] = fp[(size_t)ie * 16 + sl];
    }
    #pragma unroll
    for (int e = 0; e < 8; e++) {
      if (e >= deg) { u[e].x = 0; u[e].y = 0; u[e].z = 0; u[e].w = 0; }
      accum(u[e]);
    }
  }
  if (deg > 8) {
    uint4 u[8];
    #pragma unroll
    for (int e = 0; e < 8; e++) {
      int ie = __shfl(idx, 8 + e, 16);
      u[e] = fp[(size_t)ie * 16 + sl];
    }
    #pragma unroll
    for (int e = 0; e < 8; e++) {
      if (8 + e >= deg) { u[e].x = 0; u[e].y = 0; u[e].z = 0; u[e].w = 0; }
      accum(u[e]);
    }
  }
  for (int e = 16; e < dcap; e++) accum(fp[(size_t)S[v * 32 + e] * 16 + sl]);  // deg in (16,32]
  if (deg > 32) {                                    // never in practice
    int L = *spillc; if (L > SPILL_CAP) L = SPILL_CAP;
    for (int i2 = 0; i2 < L; i2++)
      if (spill[2 * i2] == v) accum(fp[(size_t)spill[2 * i2 + 1] * 16 + sl]);
  }

  float inv = 1.0f / (float)(deg > 1 ? deg : 1);
  float r0, r1, r2, r3, r4, r5, r6, r7;
  if (ADD) {
    uint4 tu = ((const uint4*)t)[(size_t)v * 16 + sl];
    r0 = fmaxf(a0 * inv + bf2f_lo(tu.x), 0.f); r1 = fmaxf(a1 * inv + bf2f_hi(tu.x), 0.f);
    r2 = fmaxf(a2 * inv + bf2f_lo(tu.y), 0.f); r3 = fmaxf(a3 * inv + bf2f_hi(tu.y), 0.f);
    r4 = fmaxf(a4 * inv + bf2f_lo(tu.z), 0.f); r5 = fmaxf(a5 * inv + bf2f_hi(tu.z), 0.f);
    r6 = fmaxf(a6 * inv + bf2f_lo(tu.w), 0.f); r7 = fmaxf(a7 * inv + bf2f_hi(tu.w), 0.f);
  } else {
    r0 = a0 * inv; r1 = a1 * inv; r2 = a2 * inv; r3 = a3 * inv;
    r4 = a4 * inv; r5 = a5 * inv; r6 = a6 * inv; r7 = a7 * inv;
  }
  uint4 o;
  o.x = (unsigned int)f2bf(r0) | ((unsigned int)f2bf(r1) << 16);
  o.y = (unsigned int)f2bf(r2) | ((unsigned int)f2bf(r3) << 16);
  o.z = (unsigned int)f2bf(r4) | ((unsigned int)f2bf(r5) << 16);
  o.w = (unsigned int)f2bf(r6) | ((unsigned int)f2bf(r7) << 16);
  ((uint4*)outp)[(size_t)v * 16 + sl] = o;
}

// ---------- L3 fused: out = log_softmax(mean(g[src]) + t), C=64 rows ----------
__global__ __launch_bounds__(256) void k_gather8_lsm(const unsigned short* __restrict__ g,
                                                     const unsigned short* __restrict__ t,
                                                     const int* __restrict__ cnt,
                                                     const int* __restrict__ S,
                                                     const int* __restrict__ spillc,
                                                     const int* __restrict__ spill,
                                                     float* __restrict__ out) {
  const int tid = threadIdx.x;
  const int sl = tid & 7;
  const int v = blockIdx.x * 32 + (tid >> 3);
  const int deg = cnt[v];
  const int cap8 = deg < 8 ? deg : 8;
  const int cap16 = deg < 16 ? deg : 16;
  const int dcap = deg < 32 ? deg : 32;
  int idxA = (sl < cap8) ? S[v * 32 + sl] : 0;
  int idxB = (8 + sl < cap16) ? S[v * 32 + 8 + sl] : 0;
  const uint4* fp = (const uint4*)g;                // 8 uint4 per row

  float a0 = 0.f, a1 = 0.f, a2 = 0.f, a3 = 0.f, a4 = 0.f, a5 = 0.f, a6 = 0.f, a7 = 0.f;
  auto accum = [&](uint4 u) {
    a0 += bf2f_lo(u.x); a1 += bf2f_hi(u.x);
    a2 += bf2f_lo(u.y); a3 += bf2f_hi(u.y);
    a4 += bf2f_lo(u.z); a5 += bf2f_hi(u.z);
    a6 += bf2f_lo(u.w); a7 += bf2f_hi(u.w);
  };
  {
    uint4 u[8];
    #pragma unroll
    for (int e = 0; e < 8; e++) {
      int ie = __shfl(idxA, e, 8);
      u[e] = fp[(size_t)ie * 8 + sl];
    }
    #pragma unroll
    for (int e = 0; e < 8; e++) {
      if (e >= deg) { u[e].x = 0; u[e].y = 0; u[e].z = 0; u[e].w = 0; }
      accum(u[e]);
    }
  }
  if (deg > 8) {
    uint4 u[8];
    #pragma unroll
    for (int e = 0; e < 8; e++) {
      int ie = __shfl(idxB, e, 8);
      u[e] = fp[(size_t)ie * 8 + sl];
    }
    #pragma unroll
    for (int e = 0; e < 8; e++) {
      if (8 + e >= deg) { u[e].x = 0; u[e].y = 0; u[e].z = 0; u[e].w = 0; }
      accum(u[e]);
    }
  }
  for (int e = 16; e < dcap; e++) accum(fp[(size_t)S[v * 32 + e] * 8 + sl]);
  if (deg > 32) {                                    // never in practice
    int L = *spillc; if (L > SPILL_CAP) L = SPILL_CAP;
    for (int i2 = 0; i2 < L; i2++)
      if (spill[2 * i2] == v) accum(fp[(size_t)spill[2 * i2 + 1] * 8 + sl]);
  }

  float inv = 1.0f / (float)(deg > 1 ? deg : 1);
  uint4 tu = ((const uint4*)t)[(size_t)v * 8 + sl];
  float v0 = a0 * inv + bf2f_lo(tu.x), v1 = a1 * inv + bf2f_hi(tu.x);
  float v2 = a2 * inv + bf2f_lo(tu.y), v3 = a3 * inv + bf2f_hi(tu.y);
  float v4 = a4 * inv + bf2f_lo(tu.z), v5 = a5 * inv + bf2f_hi(tu.z);
  float v6 = a6 * inv + bf2f_lo(tu.w), v7 = a7 * inv + bf2f_hi(tu.w);
  float m = fmaxf(fmaxf(fmaxf(v0, v1), fmaxf(v2, v3)), fmaxf(fmaxf(v4, v5), fmaxf(v6, v7)));
  #pragma unroll
  for (int s = 4; s; s >>= 1) m = fmaxf(m, __shfl_xor(m, s, 8));
  float sum = __expf(v0 - m) + __expf(v1 - m) + __expf(v2 - m) + __expf(v3 - m)
            + __expf(v4 - m) + __expf(v5 - m) + __expf(v6 - m) + __expf(v7 - m);
  #pragma unroll
  for (int s = 4; s; s >>= 1) sum += __shfl_xor(sum, s, 8);
  float ls = m + __logf(sum);
  float4* op = (float4*)out;
  op[(size_t)v * 16 + sl * 2 + 0] = make_float4(v0 - ls, v1 - ls, v2 - ls, v3 - ls);
  op[(size_t)v * 16 + sl * 2 + 1] = make_float4(v4 - ls, v5 - ls, v6 - ls, v7 - ls);
}

// ---------- bf16 MFMA GEMM, BK=64, XOR-swizzled LDS, coalesced repack epilogue ----------
template <int BN, bool DUAL>
__global__ __launch_bounds__(BN * 2) void k_gmm(
    const unsigned short* __restrict__ A1, const unsigned short* __restrict__ Wt1,
    const unsigned short* __restrict__ A2, const unsigned short* __restrict__ Wt2,
    const float* __restrict__ bias, int M, int K, int N,
    unsigned short* __restrict__ out1, unsigned short* __restrict__ out2, int relu) {
  constexpr int NWAVE = BN / 32;          // 4 or 2
  constexpr int ACHUNKS = 16;             // 128 rows / 8 rows-per-chunk
  constexpr int BCHUNKS = BN / 8;
  constexpr int STR = BN + 8;             // repack slab row stride
  __shared__ unsigned short smem[128 * 64 + BN * 64];
  unsigned short* As = smem;
  unsigned short* Bs = smem + 128 * 64;
  const int t = threadIdx.x;
  const int w = t >> 6, lane = t & 63;
  const int quad = lane >> 4, l15 = lane & 15;
  const int wm = w & 1, wn = w >> 1;      // BN=64: wn==0
  const int m0 = blockIdx.x * 128;
  const int n0 = DUAL ? blockIdx.y * BN : 0;
  const int srow = lane >> 3;             // row in 8-row chunk
  const int sk = (((lane & 7) ^ (srow & 7)) * 8);  // swizzled source k-offset (elems)

  const unsigned short* Wt = DUAL ? Wt1 : (blockIdx.y ? Wt2 : Wt1);
  unsigned short* out = DUAL ? out1 : (blockIdx.y ? out2 : out1);
  const float* bs = DUAL ? bias : (blockIdx.y ? bias : nullptr);

  f32x4 acc[4][4];
  #pragma unroll
  for (int i = 0; i < 4; i++)
    #pragma unroll
    for (int j = 0; j < 4; j++) acc[i][j] = (f32x4){0.f, 0.f, 0.f, 0.f};

  const int nph = DUAL ? 2 : 1;
  for (int ph = 0; ph < nph; ph++) {
    const unsigned short* A = (DUAL && ph) ? A2 : A1;
    const unsigned short* W = (DUAL && ph) ? Wt2 : Wt;
    for (int k0 = 0; k0 < K; k0 += 64) {
      #pragma unroll
      for (int c = w; c < ACHUNKS; c += NWAVE) {
        int rg = m0 + c * 8 + srow;
        if (rg >= M) rg = M - 1;          // clamp; epilogue guards stores
        async_cp16(A + (size_t)rg * K + k0 + sk, As + c * 512);
      }
      #pragma unroll
      for (int c = w; c < BCHUNKS; c += NWAVE) {
        async_cp16(W + (size_t)(n0 + c * 8 + srow) * K + k0 + sk, Bs + c * 512);
      }
      __syncthreads();
      short8 af[2][4], bfr[2][4];
      #pragma unroll
      for (int kh = 0; kh < 2; kh++) {
        #pragma unroll
        for (int mt = 0; mt < 4; mt++) {
          int r = wm * 64 + mt * 16 + l15;
          int cc = (kh * 4 + quad) ^ (r & 7);
          af[kh][mt] = *(const short8*)&As[r * 64 + cc * 8];
        }
        #pragma unroll
        for (int nt = 0; nt < 4; nt++) {
          int r = wn * 64 + nt * 16 + l15;
          int cc = (kh * 4 + quad) ^ (r & 7);
          bfr[kh][nt] = *(const short8*)&Bs[r * 64 + cc * 8];
        }
      }
      #pragma unroll
      for (int kh = 0; kh < 2; kh++)
        #pragma unroll
        for (int mt = 0; mt < 4; mt++)
          #pragma unroll
          for (int nt = 0; nt < 4; nt++)
            acc[mt][nt] = __builtin_amdgcn_mfma_f32_16x16x32_bf16(af[kh][mt], bfr[kh][nt], acc[mt][nt], 0, 0, 0);
      __syncthreads();
    }
  }

  // epilogue: repack per-mt slab (32 rows x BN cols bf16) in LDS -> 16B coalesced stores
  float bia[4];
  #pragma unroll
  for (int nt = 0; nt < 4; nt++)
    bia[nt] = bs ? bs[n0 + wn * 64 + nt * 16 + l15] : 0.f;
  constexpr int CH_PER_ROW = BN / 8;
  constexpr int TOT_CH = 32 * CH_PER_ROW;
  for (int mt = 0; mt < 4; mt++) {
    __syncthreads();
    #pragma unroll
    for (int nt = 0; nt < 4; nt++) {
      int col = wn * 64 + nt * 16 + l15;
      #pragma unroll
      for (int r = 0; r < 4; r++) {
        float v = acc[mt][nt][r] + bia[nt];
        if (relu) v = fmaxf(v, 0.f);
        smem[(wm * 16 + quad * 4 + r) * STR + col] = f2bf(v);
      }
    }
    __syncthreads();
    #pragma unroll
    for (int c = t; c < TOT_CH; c += BN * 2) {
      int row = c / CH_PER_ROW, ofs = (c % CH_PER_ROW) * 8;
      int m = m0 + (row >> 4) * 64 + mt * 16 + (row & 15);
      if (m < M)
        *(short8*)(out + (size_t)m * N + n0 + ofs) = *(const short8*)&smem[row * STR + ofs];
    }
  }
}

extern "C" void kernel_launch(void* const* d_in, const int* in_sizes, int n_in,
                              void* d_out, int out_size, void* d_ws, size_t ws_size,
                              hipStream_t stream) {
  const float* x   = (const float*)d_in[0];
  const int*   ei  = (const int*)d_in[1];
  const float* W1l = (const float*)d_in[2];
  const float* W1r = (const float*)d_in[3];
  const float* b1  = (const float*)d_in[4];
  const float* W2l = (const float*)d_in[5];
  const float* W2r = (const float*)d_in[6];
  const float* b2  = (const float*)d_in[7];
  const float* W3l = (const float*)d_in[8];
  const float* W3r = (const float*)d_in[9];
  const float* b3  = (const float*)d_in[10];
  float* out = (float*)d_out;
  const int* src = ei;
  const int* dst = ei + NE;

  char* w = (char*)d_ws;
  auto alloc = [&](size_t bytes) {
    char* p = w;
    w += (bytes + 255) & ~(size_t)255;
    return p;
  };
  int* cnt    = (int*)alloc(NN * sizeof(int));          // fully written by k_csr2
  int* combo  = (int*)alloc((256 + NB * 16) * sizeof(int));  // spillc + padded bCnt
  int* spillc = combo;
  int* bCnt   = combo + 256;
  int* S      = (int*)alloc((size_t)NN * 32 * sizeof(int));
  int* spill  = (int*)alloc(2 * SPILL_CAP * sizeof(int));
  unsigned int* bucketBuf = (unsigned int*)alloc((size_t)NB * BCAP * sizeof(unsigned int));  // 3.2MB packed
  unsigned short* xb = (unsigned short*)alloc((size_t)NN * 128 * 2);
  unsigned short* mb = (unsigned short*)alloc((size_t)NN * 128 * 2);  // L1 mean; aliased as g2
  unsigned short* h1 = (unsigned short*)alloc((size_t)NN * 256 * 2);  // aliased as g3|t3 later
  unsigned short* h2 = (unsigned short*)alloc((size_t)NN * 128 * 2);
  unsigned short* t2 = (unsigned short*)alloc((size_t)NN * 128 * 2);
  unsigned short* t1l = (unsigned short*)alloc(128 * 256 * 2);
  unsigned short* t1r = (unsigned short*)alloc(128 * 256 * 2);
  unsigned short* t2l = (unsigned short*)alloc(256 * 128 * 2);
  unsigned short* t2r = (unsigned short*)alloc(256 * 128 * 2);
  unsigned short* t3l = (unsigned short*)alloc(128 * 64 * 2);
  unsigned short* t3r = (unsigned short*)alloc(128 * 64 * 2);
  unsigned short* g2 = mb;                       // reuse: mb dead after L1 GEMM
  unsigned short* g3 = h1;                       // reuse: h1 dead after L2 GEMM
  unsigned short* t3 = h1 + (size_t)NN * 64;

  hipMemsetAsync(combo, 0, (256 + NB * 16) * sizeof(int), stream);
  // fused pass-1 bucketing + cast + weight transpose
  k_prep<<<3994, 256, 0, stream>>>(x, xb, W1l, W1r, W2l, W2r, W3l, W3r,
                                   t1l, t1r, t2l, t2r, t3l, t3r,
                                   src, dst, bucketBuf, bCnt);
  // pass-2: per-bucket CSR build (LDS atomics, local S writes)
  k_csr2<<<NB, 1024, 0, stream>>>(bucketBuf, bCnt, cnt, S, spillc, spill);

  const int MB = (NN + 127) / 128;  // 782
  const int GB16 = NN / 16;         // 6250
  const int GB32 = NN / 32;         // 3125
  // L1: h1 = relu(mean(xb)@W1l + xb@W1r + b1)
  k_gather4_128<false><<<GB16, 256, 0, stream>>>(xb, nullptr, cnt, S, spillc, spill, mb);
  k_gmm<128, true><<<dim3(MB, 2), 256, 0, stream>>>(mb, t1l, xb, t1r, b1, NN, 128, 256, h1, nullptr, 1);
  // L2: g2 = h1@W2l ; t2 = h1@W2r + b2 ; h2 = relu(mean(g2[src]) + t2)
  k_gmm<128, false><<<dim3(MB, 2), 256, 0, stream>>>(h1, t2l, nullptr, t2r, b2, NN, 256, 128, g2, t2, 0);
  k_gather4_128<true><<<GB16, 256, 0, stream>>>(g2, t2, cnt, S, spillc, spill, h2);
  // L3: g3 = h2@W3l ; t3 = h2@W3r + b3 ; out = log_softmax(mean(g3[src]) + t3)
  k_gmm<64, false><<<dim3(MB, 2), 128, 0, stream>>>(h2, t3l, nullptr, t3r, b3, NN, 128, 64, g3, t3, 0);
  k_gather8_lsm<<<GB32, 256, 0, stream>>>(g3, t3, cnt, S, spillc, spill, out);
}